// Round 3
// baseline (459.011 us; speedup 1.0000x reference)
//
#include <hip/hip_runtime.h>

typedef __attribute__((ext_vector_type(8))) __bf16 bf16x8;
typedef __attribute__((ext_vector_type(4))) float f32x4;

constexpr int BATCH = 16384;
constexpr int DIN   = 1024;
constexpr int DHID  = 1000;
constexpr int MAXA  = 3129;

// packed tile: [kt][kc(4)][rc(128)][e8(8)] bf16, 8KB per (tile,kt)
// ws layout (bytes)
constexpr size_t WS_HP  = 0;                         // Hp: 131 blk x 32 kt x 8KB = 34,340,864
constexpr size_t WS_W1P = 34340864;                  // W1p: 3 x 8 x 32 x 8KB = 6,291,456
constexpr size_t WS_W2P = 40632320;                  // W2p: 30 x 32 x 8KB = 7,864,320
constexpr size_t WS_CNT = 48496640;                  // 3 ints (64B)
constexpr size_t WS_IDX = 48496704;                  // int[3][16384]

__device__ __forceinline__ ushort f2bf(float f) {
    return __builtin_bit_cast(ushort, (__bf16)f);
}

__device__ __forceinline__ void gload16(const void* g, void* l) {
    __builtin_amdgcn_global_load_lds((const __attribute__((address_space(1))) void*)g,
                                     (__attribute__((address_space(3))) void*)l, 16, 0, 0);
}

__global__ void route_k(const float* __restrict__ qt, int* __restrict__ counts,
                        int* __restrict__ idx) {
    int i = blockIdx.x * 256 + threadIdx.x;
    if (i >= BATCH) return;
    float a = qt[3 * i], b = qt[3 * i + 1], c = qt[3 * i + 2];
    int p = 0; float m = a;
    if (b > m) { m = b; p = 1; }
    if (c > m) { m = c; p = 2; }
    int pos = atomicAdd(&counts[p], 1);
    idx[p * BATCH + pos] = i;
}

// pack W1 (f32 [1024][1000]) -> W1p[e][nb(8)][kt(32)][kc][n128][e8] bf16
__global__ void pack_w1_k(const float* __restrict__ w1_0, const float* __restrict__ w1_1,
                          const float* __restrict__ w1_2, ushort* __restrict__ W1p) {
    int g = blockIdx.x * 256 + threadIdx.x;
    int n = g & 127, kc = (g >> 7) & 3, kt = (g >> 9) & 31, nb = (g >> 14) & 7, e = g >> 17;
    const float* W = e == 0 ? w1_0 : e == 1 ? w1_1 : w1_2;
    int nn = nb * 128 + n;
    union { ushort u[8]; int4 v; } p;
#pragma unroll
    for (int j = 0; j < 8; j++) {
        int k = kt * 32 + kc * 8 + j;
        float f = (nn < DHID) ? W[(size_t)k * DHID + nn] : 0.f;
        p.u[j] = f2bf(f);
    }
    size_t off = ((size_t)((e * 8 + nb) * 32 + kt)) * 4096 + (kc * 128 + n) * 8;
    *reinterpret_cast<int4*>(W1p + off) = p.v;
}

// pack W2 (f32 [1000][ne]) -> W2p[t(30)][kt(32)][kc][n128][e8]
__global__ void pack_w2_k(const float* __restrict__ w2_0, const float* __restrict__ w2_1,
                          const float* __restrict__ w2_2, ushort* __restrict__ W2p) {
    int g = blockIdx.x * 256 + threadIdx.x;
    int n = g & 127, kc = (g >> 7) & 3, kt = (g >> 9) & 31, t = g >> 14;
    int e = (t < 1) ? 0 : (t < 5) ? 1 : 2;
    int nb = t - (e == 0 ? 0 : e == 1 ? 1 : 5);
    int ne = e == 0 ? 2 : e == 1 ? 482 : MAXA;
    const float* W = e == 0 ? w2_0 : e == 1 ? w2_1 : w2_2;
    int nn = nb * 128 + n;
    union { ushort u[8]; int4 v; } p;
#pragma unroll
    for (int j = 0; j < 8; j++) {
        int k = kt * 32 + kc * 8 + j;
        float f = (k < DHID && nn < ne) ? W[(size_t)k * ne + nn] : 0.f;
        p.u[j] = f2bf(f);
    }
    size_t off = ((size_t)(t * 32 + kt)) * 4096 + (kc * 128 + n) * 8;
    *reinterpret_cast<int4*>(W2p + off) = p.v;
}

// ---------------- GEMM1 (persistent): Hp[mblk] = tanh(hs[rows]@W1 + b1) --------------
__global__ __launch_bounds__(256, 5)
void gemm1_k(const float* __restrict__ hs, const ushort* __restrict__ W1p,
             const float* __restrict__ b1_0, const float* __restrict__ b1_1,
             const float* __restrict__ b1_2,
             const int* __restrict__ counts, const int* __restrict__ idx,
             ushort* __restrict__ Hp) {
    const int c0 = counts[0], c1 = counts[1], c2 = counts[2];
    int nb[3] = {(c0 + 127) >> 7, (c1 + 127) >> 7, (c2 + 127) >> 7};
    int cc[3] = {c0, c1, c2};
    const int T = (nb[0] + nb[1] + nb[2]) * 8;

    const int tid = threadIdx.x;
    const int lane = tid & 63, w = tid >> 6, wm = w >> 1, wn = w & 1;
    const int m_t = tid & 127, half = tid >> 7;

    __shared__ ushort Ab[2][4][128][8];
    __shared__ ushort Bb[2][4][128][8];

    for (int t = blockIdx.x; t < T; t += gridDim.x) {
        int e = 0, r = t, mbG = 0;
        while (e < 2 && r >= nb[e] * 8) { r -= nb[e] * 8; mbG += nb[e]; ++e; }
        const int lm = r >> 3, nbk = r & 7;
        mbG += lm;
        const int cnt = cc[e];
        const float* bias = e == 0 ? b1_0 : e == 1 ? b1_1 : b1_2;
        int rr = lm * 128 + m_t; if (rr >= cnt) rr = cnt - 1;
        const float* Arow = hs + (size_t)idx[e * BATCH + rr] * DIN + half * 16;
        const ushort* Btile = W1p + (size_t)((e * 8 + nbk) * 32) * 4096;

        f32x4 acc[4][4] = {};

        auto stage = [&](int b, int kt) {
            const float* ap = Arow + kt * 32;
#pragma unroll
            for (int i = 0; i < 2; ++i) {
                float4 f0 = *reinterpret_cast<const float4*>(ap + i * 8);
                float4 f1 = *reinterpret_cast<const float4*>(ap + i * 8 + 4);
                union { ushort u[8]; int4 v; } p;
                p.u[0] = f2bf(f0.x); p.u[1] = f2bf(f0.y); p.u[2] = f2bf(f0.z); p.u[3] = f2bf(f0.w);
                p.u[4] = f2bf(f1.x); p.u[5] = f2bf(f1.y); p.u[6] = f2bf(f1.z); p.u[7] = f2bf(f1.w);
                *reinterpret_cast<int4*>(&Ab[b][half * 2 + i][m_t][0]) = p.v;
            }
            const char* bs = (const char*)(Btile + (size_t)kt * 4096) + w * 2048 + lane * 16;
            char* bd = (char*)&Bb[b][0][0][0] + w * 2048;
            gload16(bs, bd);
            gload16(bs + 1024, bd + 1024);
        };
        auto compute = [&](int b) {
            bf16x8 af[4], bfr[4];
            const int kq = lane >> 4, l15 = lane & 15;
#pragma unroll
            for (int mi = 0; mi < 4; mi++) af[mi] = *reinterpret_cast<const bf16x8*>(&Ab[b][kq][wm * 64 + mi * 16 + l15][0]);
#pragma unroll
            for (int ni = 0; ni < 4; ni++) bfr[ni] = *reinterpret_cast<const bf16x8*>(&Bb[b][kq][wn * 64 + ni * 16 + l15][0]);
#pragma unroll
            for (int mi = 0; mi < 4; mi++)
#pragma unroll
                for (int ni = 0; ni < 4; ni++)
                    acc[mi][ni] = __builtin_amdgcn_mfma_f32_16x16x32_bf16(af[mi], bfr[ni], acc[mi][ni], 0, 0, 0);
        };

        stage(0, 0);
        __syncthreads();
        for (int kt = 0; kt < 32; ++kt) {
            const int cb = kt & 1;
            if (kt + 1 < 32) stage(cb ^ 1, kt + 1);
            compute(cb);
            __syncthreads();
        }

        ushort* Hblk = Hp + (size_t)mbG * (32 * 4096);
#pragma unroll
        for (int mi = 0; mi < 4; mi++) {
            const int mb = wm * 64 + mi * 16 + ((lane >> 4) << 2);
#pragma unroll
            for (int ni = 0; ni < 4; ni++) {
                const int nl = wn * 64 + ni * 16 + (lane & 15);
                const int n = nbk * 128 + nl;
                const bool live = n < DHID;
                const float bv = live ? bias[n] : 0.f;
#pragma unroll
                for (int rg = 0; rg < 4; rg++) {
                    const int m = mb + rg;
                    float v = live ? tanhf(acc[mi][ni][rg] + bv) : 0.f;
                    Hblk[(size_t)(n >> 5) * 4096 + (((n >> 3) & 3) * 128 + m) * 8 + (n & 7)] = f2bf(v);
                }
            }
        }
    }
}

// ---------------- GEMM2 (persistent): Out = Hp @ W2 + b2, plus zero tiles ------------
__global__ __launch_bounds__(256, 5)
void gemm2_k(const ushort* __restrict__ Hp, const ushort* __restrict__ W2p,
             const float* __restrict__ b2_0, const float* __restrict__ b2_1,
             const float* __restrict__ b2_2,
             const int* __restrict__ counts, const int* __restrict__ idx,
             float* __restrict__ Out) {
    const int c0 = counts[0], c1 = counts[1], c2 = counts[2];
    int nb[3]  = {(c0 + 127) >> 7, (c1 + 127) >> 7, (c2 + 127) >> 7};
    int cc[3]  = {c0, c1, c2};
    const int nbn[3]  = {1, 4, 25};
    const int nz[3]   = {24, 21, 0};
    const int toff[3] = {0, 1, 5};
    const int nel[3]  = {2, 482, MAXA};
    const int Tc = nb[0] * 1 + nb[1] * 4 + nb[2] * 25;
    const int Tz = nb[0] * 24 + nb[1] * 21;
    const int T = Tc + Tz;

    const int tid = threadIdx.x;
    const int lane = tid & 63, w = tid >> 6, wm = w >> 1, wn = w & 1;

    __shared__ ushort Ab[2][4][128][8];
    __shared__ ushort Bb[2][4][128][8];

    for (int t = blockIdx.x; t < T; t += gridDim.x) {
        if (t < Tc) {
            int e = 0, r = t, mbG = 0;
            while (e < 2 && r >= nb[e] * nbn[e]) { r -= nb[e] * nbn[e]; mbG += nb[e]; ++e; }
            const int lm = r / nbn[e], nbk = r - lm * nbn[e];
            mbG += lm;
            const int cnt = cc[e], ne = nel[e];
            const float* bias = e == 0 ? b2_0 : e == 1 ? b2_1 : b2_2;
            const ushort* Atile = Hp + (size_t)mbG * (32 * 4096);
            const ushort* Btile = W2p + (size_t)((toff[e] + nbk) * 32) * 4096;

            f32x4 acc[4][4] = {};

            auto stage = [&](int b, int kt) {
                const char* as = (const char*)(Atile + (size_t)kt * 4096) + w * 2048 + lane * 16;
                char* ad = (char*)&Ab[b][0][0][0] + w * 2048;
                gload16(as, ad);
                gload16(as + 1024, ad + 1024);
                const char* bs = (const char*)(Btile + (size_t)kt * 4096) + w * 2048 + lane * 16;
                char* bd = (char*)&Bb[b][0][0][0] + w * 2048;
                gload16(bs, bd);
                gload16(bs + 1024, bd + 1024);
            };
            auto compute = [&](int b) {
                bf16x8 af[4], bfr[4];
                const int kq = lane >> 4, l15 = lane & 15;
#pragma unroll
                for (int mi = 0; mi < 4; mi++) af[mi] = *reinterpret_cast<const bf16x8*>(&Ab[b][kq][wm * 64 + mi * 16 + l15][0]);
#pragma unroll
                for (int ni = 0; ni < 4; ni++) bfr[ni] = *reinterpret_cast<const bf16x8*>(&Bb[b][kq][wn * 64 + ni * 16 + l15][0]);
#pragma unroll
                for (int mi = 0; mi < 4; mi++)
#pragma unroll
                    for (int ni = 0; ni < 4; ni++)
                        acc[mi][ni] = __builtin_amdgcn_mfma_f32_16x16x32_bf16(af[mi], bfr[ni], acc[mi][ni], 0, 0, 0);
            };

            stage(0, 0);
            __syncthreads();
            for (int kt = 0; kt < 32; ++kt) {
                const int cb = kt & 1;
                if (kt + 1 < 32) stage(cb ^ 1, kt + 1);
                compute(cb);
                __syncthreads();
            }

            const int m0 = lm * 128;
#pragma unroll
            for (int mi = 0; mi < 4; mi++) {
                const int mb = wm * 64 + mi * 16 + ((lane >> 4) << 2);
#pragma unroll
                for (int ni = 0; ni < 4; ni++) {
                    const int ncol = nbk * 128 + wn * 64 + ni * 16 + (lane & 15);
                    if (ncol >= MAXA) continue;
                    const bool live = ncol < ne;
                    const float bv = live ? bias[ncol] : 0.f;
#pragma unroll
                    for (int rg = 0; rg < 4; rg++) {
                        const int ml = mb + rg;
                        if (m0 + ml < cnt) {
                            const int orow = idx[e * BATCH + m0 + ml];
                            Out[(size_t)orow * MAXA + ncol] = live ? (acc[mi][ni][rg] + bv) : 0.f;
                        }
                    }
                }
            }
        } else {
            // zero tile
            int e = 0, r = t - Tc;
            while (e < 2 && r >= nb[e] * nz[e]) { r -= nb[e] * nz[e]; ++e; }
            const int lm = r / nz[e], zc = r - lm * nz[e];
            const int cnt = cc[e];
            const int col0 = (e == 0 ? 128 : 512) + zc * 128;
            const int width = (MAXA - col0 < 128) ? (MAXA - col0) : 128;
            const int m0 = lm * 128;
            const int nrow = (cnt - m0 < 128) ? (cnt - m0) : 128;
            const int* rowp = idx + e * BATCH + m0;
            for (int i = tid; i < (nrow << 7); i += 256) {
                const int rl = i >> 7, ccol = i & 127;
                if (ccol < width) Out[(size_t)rowp[rl] * MAXA + col0 + ccol] = 0.f;
            }
        }
    }
}

extern "C" void kernel_launch(void* const* d_in, const int* in_sizes, int n_in,
                              void* d_out, int out_size, void* d_ws, size_t ws_size,
                              hipStream_t stream) {
    const float* hs = (const float*)d_in[0];
    const float* qt = (const float*)d_in[1];
    const float* w1_0 = (const float*)d_in[2],  *b1_0 = (const float*)d_in[3];
    const float* w2_0 = (const float*)d_in[4],  *b2_0 = (const float*)d_in[5];
    const float* w1_1 = (const float*)d_in[6],  *b1_1 = (const float*)d_in[7];
    const float* w2_1 = (const float*)d_in[8],  *b2_1 = (const float*)d_in[9];
    const float* w1_2 = (const float*)d_in[10], *b1_2 = (const float*)d_in[11];
    const float* w2_2 = (const float*)d_in[12], *b2_2 = (const float*)d_in[13];

    char* ws = (char*)d_ws;
    ushort* Hp  = (ushort*)(ws + WS_HP);
    ushort* W1p = (ushort*)(ws + WS_W1P);
    ushort* W2p = (ushort*)(ws + WS_W2P);
    int* counts = (int*)(ws + WS_CNT);
    int* idx    = (int*)(ws + WS_IDX);
    float* Out  = (float*)d_out;

    hipMemsetAsync(counts, 0, 64, stream);
    route_k<<<64, 256, 0, stream>>>(qt, counts, idx);
    pack_w1_k<<<1536, 256, 0, stream>>>(w1_0, w1_1, w1_2, W1p);
    pack_w2_k<<<1920, 256, 0, stream>>>(w2_0, w2_1, w2_2, W2p);
    gemm1_k<<<1280, 256, 0, stream>>>(hs, W1p, b1_0, b1_1, b1_2, counts, idx, Hp);
    gemm2_k<<<1280, 256, 0, stream>>>(Hp, W2p, b2_0, b2_1, b2_2, counts, idx, Out);
}

// Round 4
// 340.247 us; speedup vs baseline: 1.3491x; 1.3491x over previous
//
#include <hip/hip_runtime.h>

typedef __attribute__((ext_vector_type(8))) __bf16 bf16x8;
typedef __attribute__((ext_vector_type(4))) float f32x4;

constexpr int BATCH = 16384;
constexpr int DIN   = 1024;
constexpr int DHID  = 1000;
constexpr int MAXA  = 3129;
constexpr int MBMAX = 131;          // max m-blocks total (128 + 3 padding)

// packed tile: [kt][kc(4)][rc(128)][e8(8)] bf16, 8KB per (tile,kt)
constexpr size_t SZ_AP  = (size_t)MBMAX * 32 * 8192;   // 34,340,864
constexpr size_t SZ_HP  = SZ_AP;
constexpr size_t SZ_W1P = 3 * 8 * 32 * 8192;           // 6,291,456
constexpr size_t SZ_W2P = 30 * 32 * 8192;              // 7,864,320
constexpr size_t WS_HP  = 0;
constexpr size_t WS_W1P = WS_HP + SZ_HP;
constexpr size_t WS_W2P = WS_W1P + SZ_W1P;
constexpr size_t WS_CNT = WS_W2P + SZ_W2P;
constexpr size_t WS_IDX = WS_CNT + 64;
constexpr size_t WS_AP  = WS_IDX + 3 * BATCH * 4;      // Ap at end (fallback: d_out tail)
constexpr size_t WS_NEED = WS_AP + SZ_AP;

constexpr int PA_BLK = 2096;   // 131*32*128/256
constexpr int PW1_BLK = 1536;
constexpr int PW2_BLK = 1920;

__device__ __forceinline__ ushort f2bf(float f) {
    return __builtin_bit_cast(ushort, (__bf16)f);
}

__device__ __forceinline__ void gload16(const void* g, void* l) {
    __builtin_amdgcn_global_load_lds((const __attribute__((address_space(1))) void*)g,
                                     (__attribute__((address_space(3))) void*)l, 16, 0, 0);
}

__global__ void route_k(const float* __restrict__ qt, int* __restrict__ counts,
                        int* __restrict__ idx) {
    int i = blockIdx.x * 256 + threadIdx.x;
    if (i >= BATCH) return;
    float a = qt[3 * i], b = qt[3 * i + 1], c = qt[3 * i + 2];
    int p = 0; float m = a;
    if (b > m) { m = b; p = 1; }
    if (c > m) { m = c; p = 2; }
    int pos = atomicAdd(&counts[p], 1);
    idx[p * BATCH + pos] = i;
}

// One fused pack kernel: [0,PA) gather+convert A, [PA,PA+PW1) W1, then W2.
__global__ void pack_all_k(const float* __restrict__ hs,
                           const float* __restrict__ w1_0, const float* __restrict__ w1_1,
                           const float* __restrict__ w1_2,
                           const float* __restrict__ w2_0, const float* __restrict__ w2_1,
                           const float* __restrict__ w2_2,
                           const int* __restrict__ counts, const int* __restrict__ idx,
                           ushort* __restrict__ Ap, ushort* __restrict__ W1p,
                           ushort* __restrict__ W2p) {
    const int b = blockIdx.x, tid = threadIdx.x;
    if (b < PA_BLK) {
        // [mb(131)][kt(32)][m(128)]
        const int g = b * 256 + tid;
        const int m = g & 127, kt = (g >> 7) & 31, mb = g >> 12;
        const int c0 = counts[0], c1 = counts[1], c2 = counts[2];
        const int n0 = (c0 + 127) >> 7, n1 = (c1 + 127) >> 7, n2 = (c2 + 127) >> 7;
        if (mb >= n0 + n1 + n2) return;
        int e = 0, lm = mb, cnt = c0;
        if (lm >= n0) { lm -= n0; e = 1; cnt = c1; }
        if (e == 1 && lm >= n1) { lm -= n1; e = 2; cnt = c2; }
        int ri = lm * 128 + m; if (ri >= cnt) ri = cnt - 1;
        const float* row = hs + (size_t)idx[e * BATCH + ri] * DIN + kt * 32;
        ushort* dst = Ap + (size_t)(mb * 32 + kt) * 4096 + m * 8;
#pragma unroll
        for (int kc = 0; kc < 4; kc++) {
            float4 f0 = *reinterpret_cast<const float4*>(row + kc * 8);
            float4 f1 = *reinterpret_cast<const float4*>(row + kc * 8 + 4);
            union { ushort u[8]; int4 v; } p;
            p.u[0] = f2bf(f0.x); p.u[1] = f2bf(f0.y); p.u[2] = f2bf(f0.z); p.u[3] = f2bf(f0.w);
            p.u[4] = f2bf(f1.x); p.u[5] = f2bf(f1.y); p.u[6] = f2bf(f1.z); p.u[7] = f2bf(f1.w);
            *reinterpret_cast<int4*>(dst + kc * 1024) = p.v;
        }
    } else if (b < PA_BLK + PW1_BLK) {
        const int g = (b - PA_BLK) * 256 + tid;
        const int n = g & 127, kc = (g >> 7) & 3, kt = (g >> 9) & 31, nb = (g >> 14) & 7, e = g >> 17;
        const float* W = e == 0 ? w1_0 : e == 1 ? w1_1 : w1_2;
        const int nn = nb * 128 + n;
        union { ushort u[8]; int4 v; } p;
#pragma unroll
        for (int j = 0; j < 8; j++) {
            int k = kt * 32 + kc * 8 + j;
            float f = (nn < DHID) ? W[(size_t)k * DHID + nn] : 0.f;
            p.u[j] = f2bf(f);
        }
        *reinterpret_cast<int4*>(W1p + ((size_t)((e * 8 + nb) * 32 + kt)) * 4096 + (kc * 128 + n) * 8) = p.v;
    } else {
        const int g = (b - PA_BLK - PW1_BLK) * 256 + tid;
        const int n = g & 127, kc = (g >> 7) & 3, kt = (g >> 9) & 31, t = g >> 14;
        const int e = (t < 1) ? 0 : (t < 5) ? 1 : 2;
        const int nb = t - (e == 0 ? 0 : e == 1 ? 1 : 5);
        const int ne = e == 0 ? 2 : e == 1 ? 482 : MAXA;
        const float* W = e == 0 ? w2_0 : e == 1 ? w2_1 : w2_2;
        const int nn = nb * 128 + n;
        union { ushort u[8]; int4 v; } p;
#pragma unroll
        for (int j = 0; j < 8; j++) {
            int k = kt * 32 + kc * 8 + j;
            float f = (k < DHID && nn < ne) ? W[(size_t)k * ne + nn] : 0.f;
            p.u[j] = f2bf(f);
        }
        *reinterpret_cast<int4*>(W2p + ((size_t)(t * 32 + kt)) * 4096 + (kc * 128 + n) * 8) = p.v;
    }
}

// ---------------- GEMM1 (persistent, XCD-grouped): Hp = tanh(Ap @ W1p + b1) ----------
__global__ __launch_bounds__(256, 4)
void gemm1_k(const ushort* __restrict__ Ap, const ushort* __restrict__ W1p,
             const float* __restrict__ b1_0, const float* __restrict__ b1_1,
             const float* __restrict__ b1_2,
             const int* __restrict__ counts, ushort* __restrict__ Hp) {
    const int c0 = counts[0], c1 = counts[1], c2 = counts[2];
    const int n0 = (c0 + 127) >> 7, n1 = (c1 + 127) >> 7, n2 = (c2 + 127) >> 7;
    const int T = (n0 + n1 + n2) * 8;

    const int tid = threadIdx.x;
    const int lane = tid & 63, w = tid >> 6, wm = w >> 1, wn = w & 1;
    const int G = gridDim.x;
    const int v = (blockIdx.x & 7) * (G >> 3) + (blockIdx.x >> 3);

    __shared__ ushort Ab[2][4][128][8];
    __shared__ ushort Bb[2][4][128][8];

    for (int t = v; t < T; t += G) {
        const int mbG = t >> 3, nbk = t & 7;
        int e = 0, lm = mbG;
        if (lm >= n0) { lm -= n0; e = 1; }
        if (e == 1 && lm >= n1) { lm -= n1; e = 2; }
        const float* bias = e == 0 ? b1_0 : e == 1 ? b1_1 : b1_2;
        const char* Atile = (const char*)(Ap + (size_t)mbG * (32 * 4096));
        const char* Btile = (const char*)(W1p + (size_t)((e * 8 + nbk) * 32) * 4096);
        const int soff = w * 2048 + lane * 16;
        char* ad = (char*)&Ab[0][0][0][0] + soff - lane * 16 + lane * 16;  // keep simple below

        f32x4 acc[4][4] = {};

        auto stage = [&](int b, int kt) {
            const char* as = Atile + (size_t)kt * 8192 + soff;
            char* adl = (char*)&Ab[b][0][0][0] + w * 2048;
            gload16(as, adl);
            gload16(as + 1024, adl + 1024);
            const char* bs = Btile + (size_t)kt * 8192 + soff;
            char* bdl = (char*)&Bb[b][0][0][0] + w * 2048;
            gload16(bs, bdl);
            gload16(bs + 1024, bdl + 1024);
        };
        auto compute = [&](int b) {
            bf16x8 af[4], bfr[4];
            const int kq = lane >> 4, l15 = lane & 15;
#pragma unroll
            for (int mi = 0; mi < 4; mi++) af[mi] = *reinterpret_cast<const bf16x8*>(&Ab[b][kq][wm * 64 + mi * 16 + l15][0]);
#pragma unroll
            for (int ni = 0; ni < 4; ni++) bfr[ni] = *reinterpret_cast<const bf16x8*>(&Bb[b][kq][wn * 64 + ni * 16 + l15][0]);
#pragma unroll
            for (int mi = 0; mi < 4; mi++)
#pragma unroll
                for (int ni = 0; ni < 4; ni++)
                    acc[mi][ni] = __builtin_amdgcn_mfma_f32_16x16x32_bf16(af[mi], bfr[ni], acc[mi][ni], 0, 0, 0);
        };

        stage(0, 0);
        __syncthreads();
        for (int kt = 0; kt < 32; ++kt) {
            const int cb = kt & 1;
            if (kt + 1 < 32) stage(cb ^ 1, kt + 1);
            compute(cb);
            __syncthreads();
        }

        ushort* Hblk = Hp + (size_t)mbG * (32 * 4096);
#pragma unroll
        for (int mi = 0; mi < 4; mi++) {
            const int mb = wm * 64 + mi * 16 + ((lane >> 4) << 2);
#pragma unroll
            for (int ni = 0; ni < 4; ni++) {
                const int nl = wn * 64 + ni * 16 + (lane & 15);
                const int n = nbk * 128 + nl;
                const bool live = n < DHID;
                const float bv = live ? bias[n] : 0.f;
#pragma unroll
                for (int rg = 0; rg < 4; rg++) {
                    const int m = mb + rg;
                    float vv = live ? tanhf(acc[mi][ni][rg] + bv) : 0.f;
                    Hblk[(size_t)(n >> 5) * 4096 + (((n >> 3) & 3) * 128 + m) * 8 + (n & 7)] = f2bf(vv);
                }
            }
        }
    }
}

// ---------------- GEMM2 (persistent, XCD-grouped): Out = Hp @ W2p + b2, + zero tiles -
__global__ __launch_bounds__(256, 4)
void gemm2_k(const ushort* __restrict__ Hp, const ushort* __restrict__ W2p,
             const float* __restrict__ b2_0, const float* __restrict__ b2_1,
             const float* __restrict__ b2_2,
             const int* __restrict__ counts, const int* __restrict__ idx,
             float* __restrict__ Out) {
    const int c0 = counts[0], c1 = counts[1], c2 = counts[2];
    int nb[3]  = {(c0 + 127) >> 7, (c1 + 127) >> 7, (c2 + 127) >> 7};
    int cc[3]  = {c0, c1, c2};
    const int nbn[3]  = {1, 4, 25};
    const int nz[3]   = {24, 21, 0};
    const int toff[3] = {0, 1, 5};
    const int nel[3]  = {2, 482, MAXA};
    const int Tc = nb[0] * 1 + nb[1] * 4 + nb[2] * 25;
    const int Tz = nb[0] * 24 + nb[1] * 21;
    const int T = Tc + Tz;

    const int tid = threadIdx.x;
    const int lane = tid & 63, w = tid >> 6, wm = w >> 1, wn = w & 1;
    const int G = gridDim.x;
    const int v = (blockIdx.x & 7) * (G >> 3) + (blockIdx.x >> 3);

    __shared__ ushort Ab[2][4][128][8];
    __shared__ ushort Bb[2][4][128][8];

    for (int t = v; t < T; t += G) {
        if (t < Tc) {
            int e = 0, r = t, mbG = 0;
            while (e < 2 && r >= nb[e] * nbn[e]) { r -= nb[e] * nbn[e]; mbG += nb[e]; ++e; }
            const int lm = r / nbn[e], nbk = r - lm * nbn[e];
            mbG += lm;
            const int cnt = cc[e], ne = nel[e];
            const float* bias = e == 0 ? b2_0 : e == 1 ? b2_1 : b2_2;
            const char* Atile = (const char*)(Hp + (size_t)mbG * (32 * 4096));
            const char* Btile = (const char*)(W2p + (size_t)((toff[e] + nbk) * 32) * 4096);
            const int soff = w * 2048 + lane * 16;

            f32x4 acc[4][4] = {};

            auto stage = [&](int b, int kt) {
                const char* as = Atile + (size_t)kt * 8192 + soff;
                char* adl = (char*)&Ab[b][0][0][0] + w * 2048;
                gload16(as, adl);
                gload16(as + 1024, adl + 1024);
                const char* bs = Btile + (size_t)kt * 8192 + soff;
                char* bdl = (char*)&Bb[b][0][0][0] + w * 2048;
                gload16(bs, bdl);
                gload16(bs + 1024, bdl + 1024);
            };
            auto compute = [&](int b) {
                bf16x8 af[4], bfr[4];
                const int kq = lane >> 4, l15 = lane & 15;
#pragma unroll
                for (int mi = 0; mi < 4; mi++) af[mi] = *reinterpret_cast<const bf16x8*>(&Ab[b][kq][wm * 64 + mi * 16 + l15][0]);
#pragma unroll
                for (int ni = 0; ni < 4; ni++) bfr[ni] = *reinterpret_cast<const bf16x8*>(&Bb[b][kq][wn * 64 + ni * 16 + l15][0]);
#pragma unroll
                for (int mi = 0; mi < 4; mi++)
#pragma unroll
                    for (int ni = 0; ni < 4; ni++)
                        acc[mi][ni] = __builtin_amdgcn_mfma_f32_16x16x32_bf16(af[mi], bfr[ni], acc[mi][ni], 0, 0, 0);
            };

            stage(0, 0);
            __syncthreads();
            for (int kt = 0; kt < 32; ++kt) {
                const int cb = kt & 1;
                if (kt + 1 < 32) stage(cb ^ 1, kt + 1);
                compute(cb);
                __syncthreads();
            }

            const int m0 = lm * 128;
#pragma unroll
            for (int mi = 0; mi < 4; mi++) {
                const int mb2 = wm * 64 + mi * 16 + ((lane >> 4) << 2);
#pragma unroll
                for (int ni = 0; ni < 4; ni++) {
                    const int ncol = nbk * 128 + wn * 64 + ni * 16 + (lane & 15);
                    if (ncol >= MAXA) continue;
                    const bool live = ncol < ne;
                    const float bv = live ? bias[ncol] : 0.f;
#pragma unroll
                    for (int rg = 0; rg < 4; rg++) {
                        const int ml = mb2 + rg;
                        if (m0 + ml < cnt) {
                            const int orow = idx[e * BATCH + m0 + ml];
                            Out[(size_t)orow * MAXA + ncol] = live ? (acc[mi][ni][rg] + bv) : 0.f;
                        }
                    }
                }
            }
        } else {
            int e = 0, r = t - Tc;
            while (e < 2 && r >= nb[e] * nz[e]) { r -= nb[e] * nz[e]; ++e; }
            const int lm = r / nz[e], zc = r - lm * nz[e];
            const int cnt = cc[e];
            const int col0 = (e == 0 ? 128 : 512) + zc * 128;
            const int width = (MAXA - col0 < 128) ? (MAXA - col0) : 128;
            const int m0 = lm * 128;
            const int nrow = (cnt - m0 < 128) ? (cnt - m0) : 128;
            const int* rowp = idx + e * BATCH + m0;
            for (int i = tid; i < (nrow << 7); i += 256) {
                const int rl = i >> 7, ccol = i & 127;
                if (ccol < width) Out[(size_t)rowp[rl] * MAXA + col0 + ccol] = 0.f;
            }
        }
    }
}

extern "C" void kernel_launch(void* const* d_in, const int* in_sizes, int n_in,
                              void* d_out, int out_size, void* d_ws, size_t ws_size,
                              hipStream_t stream) {
    const float* hs = (const float*)d_in[0];
    const float* qt = (const float*)d_in[1];
    const float* w1_0 = (const float*)d_in[2],  *b1_0 = (const float*)d_in[3];
    const float* w2_0 = (const float*)d_in[4],  *b2_0 = (const float*)d_in[5];
    const float* w1_1 = (const float*)d_in[6],  *b1_1 = (const float*)d_in[7];
    const float* w2_1 = (const float*)d_in[8],  *b2_1 = (const float*)d_in[9];
    const float* w1_2 = (const float*)d_in[10], *b1_2 = (const float*)d_in[11];
    const float* w2_2 = (const float*)d_in[12], *b2_2 = (const float*)d_in[13];

    char* ws = (char*)d_ws;
    ushort* Hp  = (ushort*)(ws + WS_HP);
    ushort* W1p = (ushort*)(ws + WS_W1P);
    ushort* W2p = (ushort*)(ws + WS_W2P);
    int* counts = (int*)(ws + WS_CNT);
    int* idx    = (int*)(ws + WS_IDX);
    // Ap: ws if it fits, else tail of d_out (safe: consumed by gemm1 before gemm2 writes)
    ushort* Ap = (ws_size >= WS_NEED) ? (ushort*)(ws + WS_AP)
               : (ushort*)((char*)d_out + ((size_t)out_size * 4 - SZ_AP));
    float* Out = (float*)d_out;

    hipMemsetAsync(counts, 0, 64, stream);
    route_k<<<64, 256, 0, stream>>>(qt, counts, idx);
    pack_all_k<<<PA_BLK + PW1_BLK + PW2_BLK, 256, 0, stream>>>(
        hs, w1_0, w1_1, w1_2, w2_0, w2_1, w2_2, counts, idx, Ap, W1p, W2p);
    gemm1_k<<<1024, 256, 0, stream>>>(Ap, W1p, b1_0, b1_1, b1_2, counts, Hp);
    gemm2_k<<<1024, 256, 0, stream>>>(Hp, W2p, b2_0, b2_1, b2_2, counts, idx, Out);
}